// Round 3
// baseline (450.942 us; speedup 1.0000x reference)
//
#include <hip/hip_runtime.h>

// Problem constants (match reference)
#define N_L   90
#define N_B   20
#define N_MU  46
#define N_LF  51
#define N_CELLS (N_L * N_B * N_MU)      // 82800
#define N_OUTK  (N_LF - N_MU + 1)       // 6
#define N_PART  20000000
#define QUADS   (N_PART / 4)            // 5,000,000
#define HIST_BLOCK 1024

// ---- R=2 config: two l-ranges of 45; LDS holds 40448 of 41400 cells, the
//      last 952 cells/range spill to hardware global atomics (2.3% of mass).
#define L_PER2      45
#define RANGE_CELLS (L_PER2 * N_B * N_MU)     // 41400
#define LDS_FLOATS  40448                     // 161,792 B <= 160 KiB LDS max
#define SPILL_PER   (RANGE_CELLS - LDS_FLOATS) // 952
#define C2_MAX      128                       // grid = 2*C <= 256 blocks

// ---- R=3 fallback config (round-2 design)
#define L_PER3  30
#define SLICE3  (L_PER3 * N_B * N_MU)         // 27600 floats
#define C3_MAX  85

// ---------------- binning math --------------------------------------------
// Reference: idx = round((x - min)/dx), dx = f32((maxs-mins)/(ns-1)).
// We use rintf(fmaf(x, 1/dx, -min/dx)): biases 44.5 / 9.5 / -35 are EXACT;
// reciprocal-vs-divide differs only within ~1 ULP of .5 boundaries (a few
// particles in 20M, each worth <= 1.0 mass vs threshold 65.3).
__device__ __forceinline__ void compute_idx(float x, float y, float z,
                                            int& i0, int& i1, int& i2) {
    i0 = (int)rintf(fmaf(x, 89.0f / 180.0f, 44.5f));
    i1 = (int)rintf(fmaf(y, 19.0f / 24.0f,  9.5f));
    i2 = (int)rintf(fmaf(z, 5.0f,          -35.0f));
}

// ---------------- R=2 main path -------------------------------------------

__device__ __forceinline__ void bin2(float x, float y, float z, float m,
                                     int l_lo, float* __restrict__ s_hist,
                                     float* __restrict__ spill_r) {
    int i0, i1, i2;
    compute_idx(x, y, z, i0, i1, i2);
    int il = i0 - l_lo;
    if (((unsigned)il < L_PER2) & ((unsigned)i1 < N_B) & ((unsigned)i2 < N_MU)) {
        int f = (il * N_B + i1) * N_MU + i2;
        if (f < LDS_FLOATS) atomicAdd(&s_hist[f], m);            // ds_add_f32
        else unsafeAtomicAdd(&spill_r[f - LDS_FLOATS], m);       // HW global
    }
}

__global__ __launch_bounds__(HIST_BLOCK) void hist2_kernel(
        const float4* __restrict__ lbm4,
        const float4* __restrict__ m4,
        float* __restrict__ slices,          // [2][C][LDS_FLOATS]
        float* __restrict__ spill,           // [2][SPILL_PER], pre-zeroed
        int C, int qpc) {
    __shared__ float s_hist[LDS_FLOATS];
    int c = blockIdx.x >> 1;                 // siblings (c,0),(c,1) adjacent
    int r = blockIdx.x & 1;                  //   -> chunk data L3-hot for r=1
    int l_lo = r * L_PER2;
    float* spill_r = spill + r * SPILL_PER;

    for (int i = threadIdx.x; i < LDS_FLOATS; i += HIST_BLOCK) s_hist[i] = 0.0f;
    __syncthreads();

    int q0 = c * qpc;
    int q1 = q0 + qpc;
    if (q1 > QUADS) q1 = QUADS;
    int q = q0 + threadIdx.x;
    // 2x unroll: 8 outstanding 16B loads per thread for memory ILP
    for (; q + HIST_BLOCK < q1; q += 2 * HIST_BLOCK) {
        int p = q + HIST_BLOCK;
        float4 a0 = lbm4[3 * q + 0];
        float4 b0 = lbm4[3 * q + 1];
        float4 c0 = lbm4[3 * q + 2];
        float4 a1 = lbm4[3 * p + 0];
        float4 b1 = lbm4[3 * p + 1];
        float4 c1 = lbm4[3 * p + 2];
        float4 m0 = m4[q];
        float4 m1 = m4[p];
        bin2(a0.x, a0.y, a0.z, m0.x, l_lo, s_hist, spill_r);
        bin2(a0.w, b0.x, b0.y, m0.y, l_lo, s_hist, spill_r);
        bin2(b0.z, b0.w, c0.x, m0.z, l_lo, s_hist, spill_r);
        bin2(c0.y, c0.z, c0.w, m0.w, l_lo, s_hist, spill_r);
        bin2(a1.x, a1.y, a1.z, m1.x, l_lo, s_hist, spill_r);
        bin2(a1.w, b1.x, b1.y, m1.y, l_lo, s_hist, spill_r);
        bin2(b1.z, b1.w, c1.x, m1.z, l_lo, s_hist, spill_r);
        bin2(c1.y, c1.z, c1.w, m1.w, l_lo, s_hist, spill_r);
    }
    if (q < q1) {
        float4 a0 = lbm4[3 * q + 0];
        float4 b0 = lbm4[3 * q + 1];
        float4 c0 = lbm4[3 * q + 2];
        float4 m0 = m4[q];
        bin2(a0.x, a0.y, a0.z, m0.x, l_lo, s_hist, spill_r);
        bin2(a0.w, b0.x, b0.y, m0.y, l_lo, s_hist, spill_r);
        bin2(b0.z, b0.w, c0.x, m0.z, l_lo, s_hist, spill_r);
        bin2(c0.y, c0.z, c0.w, m0.w, l_lo, s_hist, spill_r);
    }
    __syncthreads();

    // flush: plain coalesced 16B stores, zero atomics
    float4* dst = (float4*)(slices + (size_t)(r * C + c) * LDS_FLOATS);
    float4* src = (float4*)s_hist;
    for (int i = threadIdx.x; i < LDS_FLOATS / 4; i += HIST_BLOCK) dst[i] = src[i];
}

__global__ __launch_bounds__(256) void reduce2_kernel(
        const float* __restrict__ slices,
        const float* __restrict__ spill,
        float* __restrict__ hist, int C) {
    const int VEC = LDS_FLOATS / 4;              // 10112 float4s per range
    int t = blockIdx.x * 256 + threadIdx.x;
    if (t < 2 * VEC) {
        int r = t / VEC, f4 = t - r * VEC;
        const float4* p = (const float4*)(slices + (size_t)r * C * LDS_FLOATS) + f4;
        float4 s = {0.0f, 0.0f, 0.0f, 0.0f};
        for (int cc = 0; cc < C; ++cc) {
            float4 v = p[(size_t)cc * VEC];
            s.x += v.x; s.y += v.y; s.z += v.z; s.w += v.w;
        }
        ((float4*)(hist + (size_t)r * RANGE_CELLS))[f4] = s;
    } else {
        int u = t - 2 * VEC;
        if (u < 2 * SPILL_PER) {
            int r = u / SPILL_PER, sdx = u - r * SPILL_PER;
            hist[r * RANGE_CELLS + LDS_FLOATS + sdx] = spill[r * SPILL_PER + sdx];
        }
    }
}

// ---------------- R=3 fallback path (round-2 design, fma binning) ----------

__device__ __forceinline__ void bin3(float x, float y, float z, float m,
                                     int l_lo, float* __restrict__ s_hist) {
    int i0, i1, i2;
    compute_idx(x, y, z, i0, i1, i2);
    int il = i0 - l_lo;
    if (((unsigned)il < L_PER3) & ((unsigned)i1 < N_B) & ((unsigned)i2 < N_MU))
        atomicAdd(&s_hist[(il * N_B + i1) * N_MU + i2], m);
}

__global__ __launch_bounds__(HIST_BLOCK) void hist3_kernel(
        const float4* __restrict__ lbm4,
        const float4* __restrict__ m4,
        float* __restrict__ slices, int C, int qpc) {
    __shared__ float s_hist[SLICE3];
    int c = blockIdx.x / 3;
    int r = blockIdx.x % 3;
    int l_lo = r * L_PER3;
    for (int i = threadIdx.x; i < SLICE3; i += HIST_BLOCK) s_hist[i] = 0.0f;
    __syncthreads();
    int q0 = c * qpc, q1 = q0 + qpc;
    if (q1 > QUADS) q1 = QUADS;
    for (int q = q0 + threadIdx.x; q < q1; q += HIST_BLOCK) {
        float4 a = lbm4[3 * q + 0];
        float4 b = lbm4[3 * q + 1];
        float4 d = lbm4[3 * q + 2];
        float4 m = m4[q];
        bin3(a.x, a.y, a.z, m.x, l_lo, s_hist);
        bin3(a.w, b.x, b.y, m.y, l_lo, s_hist);
        bin3(b.z, b.w, d.x, m.z, l_lo, s_hist);
        bin3(d.y, d.z, d.w, m.w, l_lo, s_hist);
    }
    __syncthreads();
    float* dst = slices + (size_t)(r * C + c) * SLICE3;
    for (int i = threadIdx.x; i < SLICE3; i += HIST_BLOCK) dst[i] = s_hist[i];
}

__global__ __launch_bounds__(256) void reduce3_kernel(
        const float* __restrict__ slices, float* __restrict__ hist, int C) {
    int j = blockIdx.x * 256 + threadIdx.x;
    if (j >= N_CELLS) return;
    int r = j / SLICE3;
    int off = j - r * SLICE3;
    const float* p = slices + (size_t)(r * C) * SLICE3 + off;
    float s = 0.0f;
    for (int c = 0; c < C; ++c) s += p[(size_t)c * SLICE3];
    hist[j] = s;
}

// ---------------- tiny-ws fallback: global atomics -------------------------

__global__ void zero_hist_kernel(float* __restrict__ hist) {
    int i = blockIdx.x * blockDim.x + threadIdx.x;
    if (i < N_CELLS) hist[i] = 0.0f;
}

__global__ __launch_bounds__(256) void hist_atomic_kernel(
        const float4* __restrict__ lbm4,
        const float4* __restrict__ m4,
        float* __restrict__ hist) {
    int q = blockIdx.x * blockDim.x + threadIdx.x;
    if (q >= QUADS) return;
    float4 a = lbm4[3 * q + 0];
    float4 b = lbm4[3 * q + 1];
    float4 d = lbm4[3 * q + 2];
    float4 m = m4[q];
    float xs[4] = {a.x, a.w, b.z, d.y};
    float ys[4] = {a.y, b.x, b.w, d.z};
    float zs[4] = {a.z, b.y, d.x, d.w};
    float ms[4] = {m.x, m.y, m.z, m.w};
    #pragma unroll
    for (int k = 0; k < 4; ++k) {
        int i0, i1, i2;
        compute_idx(xs[k], ys[k], zs[k], i0, i1, i2);
        if (((unsigned)i0 < N_L) & ((unsigned)i1 < N_B) & ((unsigned)i2 < N_MU))
            unsafeAtomicAdd(&hist[(i0 * N_B + i1) * N_MU + i2], ms[k]);
    }
}

// ---------------- conv epilogue ---------------------------------------------

__global__ __launch_bounds__(256) void conv_kernel(
        const float* __restrict__ hist,
        const float* __restrict__ lf,
        float* __restrict__ out) {
    __shared__ float s_lf[N_LF];
    int t = threadIdx.x;
    if (t < N_LF) s_lf[t] = lf[t];
    __syncthreads();
    int cell = blockIdx.x * blockDim.x + t;          // (l,b) pair, 1800 total
    if (cell < N_L * N_B) {
        float acc[N_OUTK];
        #pragma unroll
        for (int k = 0; k < N_OUTK; ++k) acc[k] = 0.0f;
        #pragma unroll 2
        for (int i = 0; i < N_MU; ++i) {
            float h = hist[cell * N_MU + i];
            #pragma unroll
            for (int k = 0; k < N_OUTK; ++k)
                acc[k] += h * s_lf[k + (N_MU - 1) - i];
        }
        #pragma unroll
        for (int k = 0; k < N_OUTK; ++k)
            out[cell * N_OUTK + k] = acc[k];
    }
}

// ---------------- launch ----------------------------------------------------

extern "C" void kernel_launch(void* const* d_in, const int* in_sizes, int n_in,
                              void* d_out, int out_size, void* d_ws, size_t ws_size,
                              hipStream_t stream) {
    const float4* lbm4 = (const float4*)d_in[0];   // [20e6, 3] f32
    const float4* m4   = (const float4*)d_in[1];   // [20e6]    f32
    const float*  lf   = (const float*)d_in[2];    // [51]      f32
    float* out = (float*)d_out;                    // [90,20,6] f32

    size_t ws_floats = ws_size / sizeof(float);

    // ---- R=2 sizing: slices[2][C][LDS_FLOATS] | spill[2][SPILL_PER] | hist
    long long avail2 = (long long)ws_floats - N_CELLS - 2 * SPILL_PER;
    int C2 = avail2 > 0 ? (int)(avail2 / (2LL * LDS_FLOATS)) : 0;
    if (C2 > C2_MAX) C2 = C2_MAX;

    if (C2 >= 32) {
        float* slices = (float*)d_ws;
        float* spill  = slices + (size_t)2 * C2 * LDS_FLOATS;
        float* hist   = spill + 2 * SPILL_PER;
        int qpc = (QUADS + C2 - 1) / C2;
        hipMemsetAsync(spill, 0, 2 * SPILL_PER * sizeof(float), stream);
        hist2_kernel<<<2 * C2, HIST_BLOCK, 0, stream>>>(lbm4, m4, slices, spill,
                                                        C2, qpc);
        int red_threads = 2 * (LDS_FLOATS / 4) + 2 * SPILL_PER;
        reduce2_kernel<<<(red_threads + 255) / 256, 256, 0, stream>>>(
            slices, spill, hist, C2);
        conv_kernel<<<(N_L * N_B + 255) / 256, 256, 0, stream>>>(hist, lf, out);
        return;
    }

    // ---- R=3 fallback
    long long avail3 = (long long)ws_floats - N_CELLS;
    int C3 = avail3 > 0 ? (int)(avail3 / (3LL * SLICE3)) : 0;
    if (C3 > C3_MAX) C3 = C3_MAX;
    if (C3 >= 8) {
        float* slices = (float*)d_ws;
        float* hist   = slices + (size_t)3 * C3 * SLICE3;
        int qpc = (QUADS + C3 - 1) / C3;
        hist3_kernel<<<3 * C3, HIST_BLOCK, 0, stream>>>(lbm4, m4, slices, C3, qpc);
        reduce3_kernel<<<(N_CELLS + 255) / 256, 256, 0, stream>>>(slices, hist, C3);
        conv_kernel<<<(N_L * N_B + 255) / 256, 256, 0, stream>>>(hist, lf, out);
        return;
    }

    // ---- tiny-ws fallback: global atomics
    float* hist = (float*)d_ws;
    zero_hist_kernel<<<(N_CELLS + 255) / 256, 256, 0, stream>>>(hist);
    hist_atomic_kernel<<<(QUADS + 255) / 256, 256, 0, stream>>>(lbm4, m4, hist);
    conv_kernel<<<(N_L * N_B + 255) / 256, 256, 0, stream>>>(hist, lf, out);
}

// Round 4
// 435.495 us; speedup vs baseline: 1.0355x; 1.0355x over previous
//
#include <hip/hip_runtime.h>

// Problem constants (match reference)
#define N_L   90
#define N_B   20
#define N_MU  46
#define N_LF  51
#define N_CELLS (N_L * N_B * N_MU)      // 82800
#define N_OUTK  (N_LF - N_MU + 1)       // 6
#define N_PART  20000000
#define QUADS   (N_PART / 4)            // 5,000,000
#define HIST_BLOCK 1024

// ---- R=2 config: two l-ranges of 45; LDS holds 40448 of 41400 cells, the
//      last 952 cells/range spill to hardware global atomics (2.3% of mass).
#define L_PER2      45
#define RANGE_CELLS (L_PER2 * N_B * N_MU)      // 41400
#define LDS_FLOATS  40448                      // 161,792 B <= 160 KiB LDS max
#define SPILL_PER   (RANGE_CELLS - LDS_FLOATS) // 952
#define C2_MAX      128                        // grid = 2*C <= 256 blocks
#define VEC2        (LDS_FLOATS / 4)           // 10112 float4 per range
#define RPARTS      4                          // reduce parallelism over C

// ---- R=3 fallback config
#define L_PER3  30
#define SLICE3  (L_PER3 * N_B * N_MU)          // 27600 floats
#define C3_MAX  85

// ---------------- binning math --------------------------------------------
// Reference: idx = round((x - min)/dx), dx = f32((maxs-mins)/(ns-1)).
// rintf(fmaf(x, 1/dx, -min/dx)): biases 44.5 / 9.5 / -35 are EXACT;
// reciprocal-vs-divide flips only values ~1 ULP from .5 boundaries
// (a few of 20M particles, each <= 1.0 mass vs threshold 65.3).
__device__ __forceinline__ void compute_idx(float x, float y, float z,
                                            int& i0, int& i1, int& i2) {
    i0 = (int)rintf(fmaf(x, 89.0f / 180.0f, 44.5f));
    i1 = (int)rintf(fmaf(y, 19.0f / 24.0f,  9.5f));
    i2 = (int)rintf(fmaf(z, 5.0f,          -35.0f));
}

// ---------------- R=2 main path -------------------------------------------

__device__ __forceinline__ void bin2v(bool v, float x, float y, float z, float m,
                                      int l_lo, float* __restrict__ s_hist,
                                      float* __restrict__ spill_r) {
    int i0, i1, i2;
    compute_idx(x, y, z, i0, i1, i2);
    int il = i0 - l_lo;
    bool ok = v & ((unsigned)il < L_PER2) & ((unsigned)i1 < N_B) &
              ((unsigned)i2 < N_MU);
    if (ok) {
        int f = (il * N_B + i1) * N_MU + i2;
        if (f < LDS_FLOATS) atomicAdd(&s_hist[f], m);            // ds_add_f32
        else unsafeAtomicAdd(&spill_r[f - LDS_FLOATS], m);       // HW global
    }
}

// process one quad (4 particles)
__device__ __forceinline__ void proc_quad(const float4& p0, const float4& p1,
                                          const float4& p2, const float4& pm,
                                          bool v, int l_lo,
                                          float* __restrict__ s_hist,
                                          float* __restrict__ spill_r) {
    bin2v(v, p0.x, p0.y, p0.z, pm.x, l_lo, s_hist, spill_r);
    bin2v(v, p0.w, p1.x, p1.y, pm.y, l_lo, s_hist, spill_r);
    bin2v(v, p1.z, p1.w, p2.x, pm.z, l_lo, s_hist, spill_r);
    bin2v(v, p2.y, p2.z, p2.w, pm.w, l_lo, s_hist, spill_r);
}

// clamped quad load — always in-bounds, bins predicated separately
__device__ __forceinline__ void load_quad(const float4* __restrict__ lbm4,
                                          const float4* __restrict__ m4, int q,
                                          float4& p0, float4& p1, float4& p2,
                                          float4& pm) {
    int l = q < QUADS ? q : (QUADS - 1);
    p0 = lbm4[3 * l + 0];
    p1 = lbm4[3 * l + 1];
    p2 = lbm4[3 * l + 2];
    pm = m4[l];
}

__global__ __launch_bounds__(HIST_BLOCK) void hist2_kernel(
        const float4* __restrict__ lbm4,
        const float4* __restrict__ m4,
        float* __restrict__ slices,          // [2][C][LDS_FLOATS]
        float* __restrict__ spill,           // [2][SPILL_PER], pre-zeroed
        int C, int qpc) {
    __shared__ float s_hist[LDS_FLOATS];
    int c = blockIdx.x >> 1;                 // siblings (c,0),(c,1) adjacent
    int r = blockIdx.x & 1;                  //   -> chunk data L3-hot for r=1
    int l_lo = r * L_PER2;
    float* spill_r = spill + r * SPILL_PER;

    for (int i = threadIdx.x; i < LDS_FLOATS; i += HIST_BLOCK) s_hist[i] = 0.0f;
    __syncthreads();

    int q0 = c * qpc;
    int q1 = q0 + qpc;
    if (q1 > QUADS) q1 = QUADS;
    const int S = HIST_BLOCK;
    // stage s covers quads {qs, qs+S} where qs = q0 + tid + 2*S*s
    int K  = (q1 - q0 + 2 * S - 1) / (2 * S);    // stages (block-uniform)
    int KH = (K + 1) / 2;                        // ping-pong pairs

    // Explicit 2-deep ping-pong: no register rotation copies, so the wait
    // for stage i's data sits AFTER stage i+1's loads are issued — >=8 KB
    // per wave stays in flight through the compute+DS phase.
    float4 Aa0, Aa1, Aa2, Aam, Ab0, Ab1, Ab2, Abm;
    float4 Ba0, Ba1, Ba2, Bam, Bb0, Bb1, Bb2, Bbm;
    int qs = q0 + (int)threadIdx.x;
    load_quad(lbm4, m4, qs,     Aa0, Aa1, Aa2, Aam);
    load_quad(lbm4, m4, qs + S, Ab0, Ab1, Ab2, Abm);
    for (int i = 0; i < KH; ++i) {
        int qB = qs + 2 * S;
        load_quad(lbm4, m4, qB,     Ba0, Ba1, Ba2, Bam);
        load_quad(lbm4, m4, qB + S, Bb0, Bb1, Bb2, Bbm);
        proc_quad(Aa0, Aa1, Aa2, Aam, qs < q1,     l_lo, s_hist, spill_r);
        proc_quad(Ab0, Ab1, Ab2, Abm, qs + S < q1, l_lo, s_hist, spill_r);
        int qA = qs + 4 * S;
        load_quad(lbm4, m4, qA,     Aa0, Aa1, Aa2, Aam);
        load_quad(lbm4, m4, qA + S, Ab0, Ab1, Ab2, Abm);
        proc_quad(Ba0, Ba1, Ba2, Bam, qB < q1,     l_lo, s_hist, spill_r);
        proc_quad(Bb0, Bb1, Bb2, Bbm, qB + S < q1, l_lo, s_hist, spill_r);
        qs = qA;
    }
    __syncthreads();

    // flush: plain coalesced 16B stores, zero atomics
    float4* dst = (float4*)(slices + (size_t)(r * C + c) * LDS_FLOATS);
    float4* src = (float4*)s_hist;
    for (int i = threadIdx.x; i < LDS_FLOATS / 4; i += HIST_BLOCK) dst[i] = src[i];
}

// reduce pass A: 4-way parallel over C — 4x the waves of the old reduce
__global__ __launch_bounds__(256) void reduce2a_kernel(
        const float* __restrict__ slices,
        float* __restrict__ partial,         // [RPARTS][2*VEC2] float4s
        int C) {
    int t = blockIdx.x * 256 + threadIdx.x;
    if (t >= RPARTS * 2 * VEC2) return;
    int pr = t / (2 * VEC2);
    int j  = t - pr * 2 * VEC2;              // [0, 2*VEC2)
    int r  = j / VEC2;
    int f4 = j - r * VEC2;
    int clo = (pr * C) / RPARTS, chi = ((pr + 1) * C) / RPARTS;
    const float4* p = (const float4*)(slices + (size_t)r * C * LDS_FLOATS) + f4;
    float4 s = {0.0f, 0.0f, 0.0f, 0.0f};
    for (int cc = clo; cc < chi; ++cc) {
        float4 v = p[(size_t)cc * VEC2];
        s.x += v.x; s.y += v.y; s.z += v.z; s.w += v.w;
    }
    ((float4*)partial)[(size_t)pr * 2 * VEC2 + j] = s;
}

// reduce pass B: combine 4 partials + place spill cells
__global__ __launch_bounds__(256) void reduce2b_kernel(
        const float* __restrict__ partial,
        const float* __restrict__ spill,
        float* __restrict__ hist) {
    int t = blockIdx.x * 256 + threadIdx.x;
    if (t < 2 * VEC2) {
        int r  = t / VEC2;
        int f4 = t - r * VEC2;
        const float4* p = (const float4*)partial + t;
        float4 s = {0.0f, 0.0f, 0.0f, 0.0f};
        #pragma unroll
        for (int pr = 0; pr < RPARTS; ++pr) {
            float4 v = p[(size_t)pr * 2 * VEC2];
            s.x += v.x; s.y += v.y; s.z += v.z; s.w += v.w;
        }
        ((float4*)(hist + (size_t)r * RANGE_CELLS))[f4] = s;
    } else {
        int u = t - 2 * VEC2;
        if (u < 2 * SPILL_PER) {
            int r = u / SPILL_PER, sdx = u - r * SPILL_PER;
            hist[r * RANGE_CELLS + LDS_FLOATS + sdx] = spill[r * SPILL_PER + sdx];
        }
    }
}

// ---------------- R=3 fallback path ----------------------------------------

__device__ __forceinline__ void bin3(float x, float y, float z, float m,
                                     int l_lo, float* __restrict__ s_hist) {
    int i0, i1, i2;
    compute_idx(x, y, z, i0, i1, i2);
    int il = i0 - l_lo;
    if (((unsigned)il < L_PER3) & ((unsigned)i1 < N_B) & ((unsigned)i2 < N_MU))
        atomicAdd(&s_hist[(il * N_B + i1) * N_MU + i2], m);
}

__global__ __launch_bounds__(HIST_BLOCK) void hist3_kernel(
        const float4* __restrict__ lbm4,
        const float4* __restrict__ m4,
        float* __restrict__ slices, int C, int qpc) {
    __shared__ float s_hist[SLICE3];
    int c = blockIdx.x / 3;
    int r = blockIdx.x % 3;
    int l_lo = r * L_PER3;
    for (int i = threadIdx.x; i < SLICE3; i += HIST_BLOCK) s_hist[i] = 0.0f;
    __syncthreads();
    int q0 = c * qpc, q1 = q0 + qpc;
    if (q1 > QUADS) q1 = QUADS;
    for (int q = q0 + threadIdx.x; q < q1; q += HIST_BLOCK) {
        float4 a = lbm4[3 * q + 0];
        float4 b = lbm4[3 * q + 1];
        float4 d = lbm4[3 * q + 2];
        float4 m = m4[q];
        bin3(a.x, a.y, a.z, m.x, l_lo, s_hist);
        bin3(a.w, b.x, b.y, m.y, l_lo, s_hist);
        bin3(b.z, b.w, d.x, m.z, l_lo, s_hist);
        bin3(d.y, d.z, d.w, m.w, l_lo, s_hist);
    }
    __syncthreads();
    float* dst = slices + (size_t)(r * C + c) * SLICE3;
    for (int i = threadIdx.x; i < SLICE3; i += HIST_BLOCK) dst[i] = s_hist[i];
}

__global__ __launch_bounds__(256) void reduce3_kernel(
        const float* __restrict__ slices, float* __restrict__ hist, int C) {
    int j = blockIdx.x * 256 + threadIdx.x;
    if (j >= N_CELLS) return;
    int r = j / SLICE3;
    int off = j - r * SLICE3;
    const float* p = slices + (size_t)(r * C) * SLICE3 + off;
    float s = 0.0f;
    for (int c = 0; c < C; ++c) s += p[(size_t)c * SLICE3];
    hist[j] = s;
}

// ---------------- tiny-ws fallback: global atomics -------------------------

__global__ void zero_hist_kernel(float* __restrict__ hist) {
    int i = blockIdx.x * blockDim.x + threadIdx.x;
    if (i < N_CELLS) hist[i] = 0.0f;
}

__global__ __launch_bounds__(256) void hist_atomic_kernel(
        const float4* __restrict__ lbm4,
        const float4* __restrict__ m4,
        float* __restrict__ hist) {
    int q = blockIdx.x * blockDim.x + threadIdx.x;
    if (q >= QUADS) return;
    float4 a = lbm4[3 * q + 0];
    float4 b = lbm4[3 * q + 1];
    float4 d = lbm4[3 * q + 2];
    float4 m = m4[q];
    float xs[4] = {a.x, a.w, b.z, d.y};
    float ys[4] = {a.y, b.x, b.w, d.z};
    float zs[4] = {a.z, b.y, d.x, d.w};
    float ms[4] = {m.x, m.y, m.z, m.w};
    #pragma unroll
    for (int k = 0; k < 4; ++k) {
        int i0, i1, i2;
        compute_idx(xs[k], ys[k], zs[k], i0, i1, i2);
        if (((unsigned)i0 < N_L) & ((unsigned)i1 < N_B) & ((unsigned)i2 < N_MU))
            unsafeAtomicAdd(&hist[(i0 * N_B + i1) * N_MU + i2], ms[k]);
    }
}

// ---------------- conv epilogue ---------------------------------------------

__global__ __launch_bounds__(256) void conv_kernel(
        const float* __restrict__ hist,
        const float* __restrict__ lf,
        float* __restrict__ out) {
    __shared__ float s_lf[N_LF];
    int t = threadIdx.x;
    if (t < N_LF) s_lf[t] = lf[t];
    __syncthreads();
    int cell = blockIdx.x * blockDim.x + t;          // (l,b) pair, 1800 total
    if (cell < N_L * N_B) {
        float acc[N_OUTK];
        #pragma unroll
        for (int k = 0; k < N_OUTK; ++k) acc[k] = 0.0f;
        #pragma unroll 2
        for (int i = 0; i < N_MU; ++i) {
            float h = hist[cell * N_MU + i];
            #pragma unroll
            for (int k = 0; k < N_OUTK; ++k)
                acc[k] += h * s_lf[k + (N_MU - 1) - i];
        }
        #pragma unroll
        for (int k = 0; k < N_OUTK; ++k)
            out[cell * N_OUTK + k] = acc[k];
    }
}

// ---------------- launch ----------------------------------------------------

extern "C" void kernel_launch(void* const* d_in, const int* in_sizes, int n_in,
                              void* d_out, int out_size, void* d_ws, size_t ws_size,
                              hipStream_t stream) {
    const float4* lbm4 = (const float4*)d_in[0];   // [20e6, 3] f32
    const float4* m4   = (const float4*)d_in[1];   // [20e6]    f32
    const float*  lf   = (const float*)d_in[2];    // [51]      f32
    float* out = (float*)d_out;                    // [90,20,6] f32

    size_t ws_floats = ws_size / sizeof(float);
    const long long PARTIAL_FLOATS = (long long)RPARTS * 2 * VEC2 * 4;

    // ---- R=2 sizing: slices | partial | spill | hist
    long long avail2 = (long long)ws_floats - N_CELLS - 2 * SPILL_PER
                       - PARTIAL_FLOATS;
    int C2 = avail2 > 0 ? (int)(avail2 / (2LL * LDS_FLOATS)) : 0;
    if (C2 > C2_MAX) C2 = C2_MAX;

    if (C2 >= 32) {
        float* slices  = (float*)d_ws;
        float* partial = slices + (size_t)2 * C2 * LDS_FLOATS;
        float* spill   = partial + PARTIAL_FLOATS;
        float* hist    = spill + 2 * SPILL_PER;
        int qpc = (QUADS + C2 - 1) / C2;
        hipMemsetAsync(spill, 0, 2 * SPILL_PER * sizeof(float), stream);
        hist2_kernel<<<2 * C2, HIST_BLOCK, 0, stream>>>(lbm4, m4, slices, spill,
                                                        C2, qpc);
        int ta = RPARTS * 2 * VEC2;
        reduce2a_kernel<<<(ta + 255) / 256, 256, 0, stream>>>(slices, partial, C2);
        int tb = 2 * VEC2 + 2 * SPILL_PER;
        reduce2b_kernel<<<(tb + 255) / 256, 256, 0, stream>>>(partial, spill, hist);
        conv_kernel<<<(N_L * N_B + 255) / 256, 256, 0, stream>>>(hist, lf, out);
        return;
    }

    // ---- R=3 fallback
    long long avail3 = (long long)ws_floats - N_CELLS;
    int C3 = avail3 > 0 ? (int)(avail3 / (3LL * SLICE3)) : 0;
    if (C3 > C3_MAX) C3 = C3_MAX;
    if (C3 >= 8) {
        float* slices = (float*)d_ws;
        float* hist   = slices + (size_t)3 * C3 * SLICE3;
        int qpc = (QUADS + C3 - 1) / C3;
        hist3_kernel<<<3 * C3, HIST_BLOCK, 0, stream>>>(lbm4, m4, slices, C3, qpc);
        reduce3_kernel<<<(N_CELLS + 255) / 256, 256, 0, stream>>>(slices, hist, C3);
        conv_kernel<<<(N_L * N_B + 255) / 256, 256, 0, stream>>>(hist, lf, out);
        return;
    }

    // ---- tiny-ws fallback: global atomics
    float* hist = (float*)d_ws;
    zero_hist_kernel<<<(N_CELLS + 255) / 256, 256, 0, stream>>>(hist);
    hist_atomic_kernel<<<(QUADS + 255) / 256, 256, 0, stream>>>(lbm4, m4, hist);
    conv_kernel<<<(N_L * N_B + 255) / 256, 256, 0, stream>>>(hist, lf, out);
}

// Round 5
// 419.224 us; speedup vs baseline: 1.0757x; 1.0388x over previous
//
#include <hip/hip_runtime.h>

// Problem constants (match reference)
#define N_L   90
#define N_B   20
#define N_MU  46
#define N_LF  51
#define N_CELLS (N_L * N_B * N_MU)      // 82800
#define N_OUTK  (N_LF - N_MU + 1)       // 6
#define N_PART  20000000
#define QUADS   (N_PART / 4)            // 5,000,000
#define HIST_BLOCK 1024

// ---- R=2 config: two l-ranges of 45. LDS = full 160 KiB = 40960 u32 cells;
//      last 440 cells/range (1.06% of mass) spill to HW global u32 atomics.
#define L_PER2      45
#define RANGE_CELLS (L_PER2 * N_B * N_MU)      // 41400
#define LDS_CELLS   40960                      // 163,840 B = 160 KiB exactly
#define SPILL_PER   (RANGE_CELLS - LDS_CELLS)  // 440
#define C2_MAX      128                        // grid = 2*C <= 256 blocks
#define VEC2        (LDS_CELLS / 4)            // 10240 uint4 per range
#define RPARTS      4                          // reduce parallelism over C

// Fixed-point mass scale: 2^23. Cell sums < 350 particles * 2^23 = 2.9e9 < 2^32.
#define MSCALE      8388608.0f
#define MSCALE_INV  (1.0f / 8388608.0f)

// ---- R=3 fallback config (f32, round-2 design)
#define L_PER3  30
#define SLICE3  (L_PER3 * N_B * N_MU)          // 27600 floats
#define C3_MAX  85

// ---------------- binning math --------------------------------------------
// Reference: idx = round((x - min)/dx), dx = f32((maxs-mins)/(ns-1)).
// rintf(fmaf(x, 1/dx, -min/dx)): biases 44.5 / 9.5 / -35 are EXACT;
// reciprocal-vs-divide flips only values ~1 ULP from .5 boundaries.
__device__ __forceinline__ void compute_idx(float x, float y, float z,
                                            int& i0, int& i1, int& i2) {
    i0 = (int)rintf(fmaf(x, 89.0f / 180.0f, 44.5f));
    i1 = (int)rintf(fmaf(y, 19.0f / 24.0f,  9.5f));
    i2 = (int)rintf(fmaf(z, 5.0f,          -35.0f));
}

// ---------------- R=2 main path (u32 fixed-point) --------------------------

__device__ __forceinline__ void bin2u(bool v, float x, float y, float z, float m,
                                      int l_lo, unsigned* __restrict__ s_hist,
                                      unsigned* __restrict__ spill_r) {
    int i0, i1, i2;
    compute_idx(x, y, z, i0, i1, i2);
    int il = i0 - l_lo;
    bool ok = v & ((unsigned)il < L_PER2) & ((unsigned)i1 < N_B) &
              ((unsigned)i2 < N_MU);
    if (ok) {
        unsigned mu = (unsigned)(int)rintf(m * MSCALE);   // 23-bit fixed point
        int f = (il * N_B + i1) * N_MU + i2;
        if (f < LDS_CELLS) atomicAdd(&s_hist[f], mu);             // ds_add_u32
        else atomicAdd(&spill_r[f - LDS_CELLS], mu);              // HW global u32
    }
}

__global__ __launch_bounds__(HIST_BLOCK) void hist2_kernel(
        const float4* __restrict__ lbm4,
        const float4* __restrict__ m4,
        unsigned* __restrict__ slices,       // [2][C][LDS_CELLS]
        unsigned* __restrict__ spill,        // [2][SPILL_PER], pre-zeroed
        int C, int qpc) {
    __shared__ unsigned s_hist[LDS_CELLS];
    // XCD-paired mapping (requires C % 8 == 0, grid = 2C a multiple of 16):
    // bid = 16*(c/8) + 8*r + (c%8)  ->  siblings (c,0),(c,1) differ by 8
    // -> same XCD under round-robin bid%8 -> 2nd read of the 2.5 MB chunk
    // merges in that XCD's 4 MB L2 instead of crossing to L3.
    int bid = blockIdx.x;
    int r   = (bid >> 3) & 1;
    int c   = ((bid >> 4) << 3) + (bid & 7);
    int l_lo = r * L_PER2;
    unsigned* spill_r = spill + r * SPILL_PER;

    // zero LDS via b128 writes
    uint4* sh4 = (uint4*)s_hist;
    #pragma unroll
    for (int i = threadIdx.x; i < LDS_CELLS / 4; i += HIST_BLOCK)
        sh4[i] = make_uint4(0u, 0u, 0u, 0u);
    __syncthreads();

    int q0 = c * qpc;
    int q1 = q0 + qpc;
    if (q1 > QUADS) q1 = QUADS;
    const int S = HIST_BLOCK;
    for (int q = q0 + (int)threadIdx.x; q < q1; q += 2 * S) {
        int p  = q + S;
        bool vp = p < q1;
        int pl = vp ? p : q;
        float4 a0 = lbm4[3 * q + 0];
        float4 b0 = lbm4[3 * q + 1];
        float4 c0 = lbm4[3 * q + 2];
        float4 a1 = lbm4[3 * pl + 0];
        float4 b1 = lbm4[3 * pl + 1];
        float4 c1 = lbm4[3 * pl + 2];
        float4 m0 = m4[q];
        float4 m1 = m4[pl];
        bin2u(true, a0.x, a0.y, a0.z, m0.x, l_lo, s_hist, spill_r);
        bin2u(true, a0.w, b0.x, b0.y, m0.y, l_lo, s_hist, spill_r);
        bin2u(true, b0.z, b0.w, c0.x, m0.z, l_lo, s_hist, spill_r);
        bin2u(true, c0.y, c0.z, c0.w, m0.w, l_lo, s_hist, spill_r);
        bin2u(vp, a1.x, a1.y, a1.z, m1.x, l_lo, s_hist, spill_r);
        bin2u(vp, a1.w, b1.x, b1.y, m1.y, l_lo, s_hist, spill_r);
        bin2u(vp, b1.z, b1.w, c1.x, m1.z, l_lo, s_hist, spill_r);
        bin2u(vp, c1.y, c1.z, c1.w, m1.w, l_lo, s_hist, spill_r);
    }
    __syncthreads();

    // flush: plain coalesced 16B stores, zero atomics
    uint4* dst = (uint4*)(slices + (size_t)(r * C + c) * LDS_CELLS);
    #pragma unroll
    for (int i = threadIdx.x; i < LDS_CELLS / 4; i += HIST_BLOCK)
        dst[i] = sh4[i];
}

// reduce pass A: 4-way parallel over C (u32 sums cannot overflow: total
// scaled mass per cell < 350 * 2^23 = 2.9e9 < 2^32)
__global__ __launch_bounds__(256) void reduce2a_kernel(
        const unsigned* __restrict__ slices,
        unsigned* __restrict__ partial,      // [RPARTS][2*VEC2] uint4
        int C) {
    int t = blockIdx.x * 256 + threadIdx.x;
    if (t >= RPARTS * 2 * VEC2) return;
    int pr = t / (2 * VEC2);
    int j  = t - pr * 2 * VEC2;
    int r  = j / VEC2;
    int f4 = j - r * VEC2;
    int clo = (pr * C) / RPARTS, chi = ((pr + 1) * C) / RPARTS;
    const uint4* p = (const uint4*)(slices + (size_t)r * C * LDS_CELLS) + f4;
    uint4 s = make_uint4(0u, 0u, 0u, 0u);
    for (int cc = clo; cc < chi; ++cc) {
        uint4 v = p[(size_t)cc * VEC2];
        s.x += v.x; s.y += v.y; s.z += v.z; s.w += v.w;
    }
    ((uint4*)partial)[(size_t)pr * 2 * VEC2 + j] = s;
}

// reduce pass B: combine partials + spill cells, convert to f32
__global__ __launch_bounds__(256) void reduce2b_kernel(
        const unsigned* __restrict__ partial,
        const unsigned* __restrict__ spill,
        float* __restrict__ hist) {
    int t = blockIdx.x * 256 + threadIdx.x;
    if (t < 2 * VEC2) {
        int r  = t / VEC2;
        int f4 = t - r * VEC2;
        const uint4* p = (const uint4*)partial + t;
        uint4 s = make_uint4(0u, 0u, 0u, 0u);
        #pragma unroll
        for (int pr = 0; pr < RPARTS; ++pr) {
            uint4 v = p[(size_t)pr * 2 * VEC2];
            s.x += v.x; s.y += v.y; s.z += v.z; s.w += v.w;
        }
        float4 f;
        f.x = (float)s.x * MSCALE_INV;
        f.y = (float)s.y * MSCALE_INV;
        f.z = (float)s.z * MSCALE_INV;
        f.w = (float)s.w * MSCALE_INV;
        ((float4*)(hist + (size_t)r * RANGE_CELLS))[f4] = f;
    } else {
        int u = t - 2 * VEC2;
        if (u < 2 * SPILL_PER) {
            int r = u / SPILL_PER, sdx = u - r * SPILL_PER;
            hist[r * RANGE_CELLS + LDS_CELLS + sdx] =
                (float)spill[r * SPILL_PER + sdx] * MSCALE_INV;
        }
    }
}

// ---------------- R=3 fallback path (f32, unchanged) ------------------------

__device__ __forceinline__ void bin3(float x, float y, float z, float m,
                                     int l_lo, float* __restrict__ s_hist) {
    int i0, i1, i2;
    compute_idx(x, y, z, i0, i1, i2);
    int il = i0 - l_lo;
    if (((unsigned)il < L_PER3) & ((unsigned)i1 < N_B) & ((unsigned)i2 < N_MU))
        atomicAdd(&s_hist[(il * N_B + i1) * N_MU + i2], m);
}

__global__ __launch_bounds__(HIST_BLOCK) void hist3_kernel(
        const float4* __restrict__ lbm4,
        const float4* __restrict__ m4,
        float* __restrict__ slices, int C, int qpc) {
    __shared__ float s_hist[SLICE3];
    int c = blockIdx.x / 3;
    int r = blockIdx.x % 3;
    int l_lo = r * L_PER3;
    for (int i = threadIdx.x; i < SLICE3; i += HIST_BLOCK) s_hist[i] = 0.0f;
    __syncthreads();
    int q0 = c * qpc, q1 = q0 + qpc;
    if (q1 > QUADS) q1 = QUADS;
    for (int q = q0 + threadIdx.x; q < q1; q += HIST_BLOCK) {
        float4 a = lbm4[3 * q + 0];
        float4 b = lbm4[3 * q + 1];
        float4 d = lbm4[3 * q + 2];
        float4 m = m4[q];
        bin3(a.x, a.y, a.z, m.x, l_lo, s_hist);
        bin3(a.w, b.x, b.y, m.y, l_lo, s_hist);
        bin3(b.z, b.w, d.x, m.z, l_lo, s_hist);
        bin3(d.y, d.z, d.w, m.w, l_lo, s_hist);
    }
    __syncthreads();
    float* dst = slices + (size_t)(r * C + c) * SLICE3;
    for (int i = threadIdx.x; i < SLICE3; i += HIST_BLOCK) dst[i] = s_hist[i];
}

__global__ __launch_bounds__(256) void reduce3_kernel(
        const float* __restrict__ slices, float* __restrict__ hist, int C) {
    int j = blockIdx.x * 256 + threadIdx.x;
    if (j >= N_CELLS) return;
    int r = j / SLICE3;
    int off = j - r * SLICE3;
    const float* p = slices + (size_t)(r * C) * SLICE3 + off;
    float s = 0.0f;
    for (int c = 0; c < C; ++c) s += p[(size_t)c * SLICE3];
    hist[j] = s;
}

// ---------------- tiny-ws fallback: global f32 atomics ----------------------

__global__ void zero_hist_kernel(float* __restrict__ hist) {
    int i = blockIdx.x * blockDim.x + threadIdx.x;
    if (i < N_CELLS) hist[i] = 0.0f;
}

__global__ __launch_bounds__(256) void hist_atomic_kernel(
        const float4* __restrict__ lbm4,
        const float4* __restrict__ m4,
        float* __restrict__ hist) {
    int q = blockIdx.x * blockDim.x + threadIdx.x;
    if (q >= QUADS) return;
    float4 a = lbm4[3 * q + 0];
    float4 b = lbm4[3 * q + 1];
    float4 d = lbm4[3 * q + 2];
    float4 m = m4[q];
    float xs[4] = {a.x, a.w, b.z, d.y};
    float ys[4] = {a.y, b.x, b.w, d.z};
    float zs[4] = {a.z, b.y, d.x, d.w};
    float ms[4] = {m.x, m.y, m.z, m.w};
    #pragma unroll
    for (int k = 0; k < 4; ++k) {
        int i0, i1, i2;
        compute_idx(xs[k], ys[k], zs[k], i0, i1, i2);
        if (((unsigned)i0 < N_L) & ((unsigned)i1 < N_B) & ((unsigned)i2 < N_MU))
            unsafeAtomicAdd(&hist[(i0 * N_B + i1) * N_MU + i2], ms[k]);
    }
}

// ---------------- conv epilogue ---------------------------------------------

__global__ __launch_bounds__(256) void conv_kernel(
        const float* __restrict__ hist,
        const float* __restrict__ lf,
        float* __restrict__ out) {
    __shared__ float s_lf[N_LF];
    int t = threadIdx.x;
    if (t < N_LF) s_lf[t] = lf[t];
    __syncthreads();
    int cell = blockIdx.x * blockDim.x + t;          // (l,b) pair, 1800 total
    if (cell < N_L * N_B) {
        float acc[N_OUTK];
        #pragma unroll
        for (int k = 0; k < N_OUTK; ++k) acc[k] = 0.0f;
        #pragma unroll 2
        for (int i = 0; i < N_MU; ++i) {
            float h = hist[cell * N_MU + i];
            #pragma unroll
            for (int k = 0; k < N_OUTK; ++k)
                acc[k] += h * s_lf[k + (N_MU - 1) - i];
        }
        #pragma unroll
        for (int k = 0; k < N_OUTK; ++k)
            out[cell * N_OUTK + k] = acc[k];
    }
}

// ---------------- launch ----------------------------------------------------

extern "C" void kernel_launch(void* const* d_in, const int* in_sizes, int n_in,
                              void* d_out, int out_size, void* d_ws, size_t ws_size,
                              hipStream_t stream) {
    const float4* lbm4 = (const float4*)d_in[0];   // [20e6, 3] f32
    const float4* m4   = (const float4*)d_in[1];   // [20e6]    f32
    const float*  lf   = (const float*)d_in[2];    // [51]      f32
    float* out = (float*)d_out;                    // [90,20,6] f32

    size_t ws_words = ws_size / 4;                 // u32/f32 units
    const long long PARTIAL_WORDS = (long long)RPARTS * 2 * VEC2 * 4;

    // ---- R=2 sizing: slices(u32) | partial(u32) | spill(u32) | hist(f32)
    long long avail2 = (long long)ws_words - N_CELLS - 2 * SPILL_PER
                       - PARTIAL_WORDS;
    int C2 = avail2 > 0 ? (int)(avail2 / (2LL * LDS_CELLS)) : 0;
    if (C2 > C2_MAX) C2 = C2_MAX;
    C2 &= ~7;                                      // XCD pairing needs C2 % 8 == 0

    if (C2 >= 32) {
        unsigned* slices  = (unsigned*)d_ws;
        unsigned* partial = slices + (size_t)2 * C2 * LDS_CELLS;
        unsigned* spill   = partial + PARTIAL_WORDS;
        float*    hist    = (float*)(spill + 2 * SPILL_PER);
        int qpc = (QUADS + C2 - 1) / C2;
        hipMemsetAsync(spill, 0, 2 * SPILL_PER * sizeof(unsigned), stream);
        hist2_kernel<<<2 * C2, HIST_BLOCK, 0, stream>>>(lbm4, m4, slices, spill,
                                                        C2, qpc);
        int ta = RPARTS * 2 * VEC2;
        reduce2a_kernel<<<(ta + 255) / 256, 256, 0, stream>>>(slices, partial, C2);
        int tb = 2 * VEC2 + 2 * SPILL_PER;
        reduce2b_kernel<<<(tb + 255) / 256, 256, 0, stream>>>(partial, spill, hist);
        conv_kernel<<<(N_L * N_B + 255) / 256, 256, 0, stream>>>(hist, lf, out);
        return;
    }

    // ---- R=3 fallback (f32)
    long long avail3 = (long long)ws_words - N_CELLS;
    int C3 = avail3 > 0 ? (int)(avail3 / (3LL * SLICE3)) : 0;
    if (C3 > C3_MAX) C3 = C3_MAX;
    if (C3 >= 8) {
        float* slices = (float*)d_ws;
        float* hist   = slices + (size_t)3 * C3 * SLICE3;
        int qpc = (QUADS + C3 - 1) / C3;
        hist3_kernel<<<3 * C3, HIST_BLOCK, 0, stream>>>(lbm4, m4, slices, C3, qpc);
        reduce3_kernel<<<(N_CELLS + 255) / 256, 256, 0, stream>>>(slices, hist, C3);
        conv_kernel<<<(N_L * N_B + 255) / 256, 256, 0, stream>>>(hist, lf, out);
        return;
    }

    // ---- tiny-ws fallback: global atomics
    float* hist = (float*)d_ws;
    zero_hist_kernel<<<(N_CELLS + 255) / 256, 256, 0, stream>>>(hist);
    hist_atomic_kernel<<<(QUADS + 255) / 256, 256, 0, stream>>>(lbm4, m4, hist);
    conv_kernel<<<(N_L * N_B + 255) / 256, 256, 0, stream>>>(hist, lf, out);
}